// Round 9
// baseline (199.663 us; speedup 1.0000x reference)
//
#include <hip/hip_runtime.h>
#include <hip/hip_bf16.h>

#define NUM_CLASSES 80
#define BATCH 8
#define N20 1200
#define N40 4800
#define N80 19200
#define NANCH 25200
#define NEGV  -1000000000.0f
#define SCORE_THR 0.25f
#define CAP 1024            // per-batch candidate capacity (expected ~490)
#define RMAX 192            // ranks materialized in the suppression matrix
#define PKCAP 512           // prefiltered participant capacity
#define NHBIN 1024          // histogram bins over the [64,128) octave
#define THR_LIST 64.0f      // list threshold (exact float)
#define NPB 99              // producer blocks per batch (99*256 >= 25200)

typedef unsigned long long ull;

// exact IEEE fp32 (no FMA contraction) "IoU > 0.5" — matches numpy ref
__device__ __forceinline__ bool iou_gt(const float4 A, float areaA, const float4 Bx, float areaB) {
    float ih = fmaxf(__fsub_rn(fminf(A.z, Bx.z), fmaxf(A.x, Bx.x)), 0.0f);
    float iw = fmaxf(__fsub_rn(fminf(A.w, Bx.w), fmaxf(A.y, Bx.y)), 0.0f);
    float inter = __fmul_rn(ih, iw);
    float uni = __fsub_rn(__fadd_rn(areaA, areaB), inter);
    if (!(uni > 0.0f)) return false;
    return __fdiv_rn(inter, uni) > 0.5f;
}

__device__ __forceinline__ float4 load_box(int b, int n,
        const float* b20, const float* b40, const float* b80) {
    if (n < N20)       return ((const float4*)b20)[(size_t)b * N20 + n];
    if (n < N20 + N40) return ((const float4*)b40)[(size_t)b * N40 + (n - N20)];
    return ((const float4*)b80)[(size_t)b * N80 + (n - N20 - N40)];
}

__device__ __forceinline__ float box_area(const float4 B) {
    return __fmul_rn(__fsub_rn(B.z, B.x), __fsub_rn(B.w, B.y));
}

__device__ __forceinline__ int key_idx(ull k) {
    return (int)(0xFFFFFFFFu - (unsigned)(k & 0xFFFFFFFFull));
}

// ---------------------------------------------------------------------------
// Fused kernel: blocks [0, 8*NPB) = score producers (R8-proven body);
// blocks [8*NPB, 8*NPB+8) = per-batch NMS consumers (spin on done_cnt).
// All 800 blocks co-resident (256 thr, ~25 KB LDS -> 6 blk/CU * 256 CU).
// ---------------------------------------------------------------------------
__global__ __launch_bounds__(256) void fused_kernel(
        const float* __restrict__ b20, const float* __restrict__ p20, const float* __restrict__ c20,
        const float* __restrict__ b40, const float* __restrict__ p40, const float* __restrict__ c40,
        const float* __restrict__ b80, const float* __restrict__ p80, const float* __restrict__ c80,
        float* __restrict__ scores, unsigned* __restrict__ cand_cnt,
        unsigned* __restrict__ done_cnt, ull* __restrict__ cand_keys,
        float* __restrict__ out) {
    __shared__ ull skeys[CAP];          // 8 KB (guard-path rank source)
    __shared__ ull pk[PKCAP];           // 4 KB participants
    __shared__ unsigned hist[NHBIN];    // 4 KB
    __shared__ ull srt_key[RMAX];       // 1.5 KB
    __shared__ float4 bbox[RMAX];       // 3 KB
    __shared__ ull M[RMAX][3];          // 4.5 KB
    __shared__ ull red[256];            // 2 KB (fallback argmax reduce)
    __shared__ int sh_V, sh_T;
    __shared__ unsigned sh_pcnt;

    const int t = threadIdx.x;
    const int lane = t & 63;
    const int blk = blockIdx.x;

    if (blk < BATCH * NPB) {
        // ----------------------------- producer ---------------------------
        const int b = blk / NPB;
        const int r = blk - b * NPB;
        const int an = r * 256 + t;
        const bool valid_an = (an < NANCH);
        const int n = valid_an ? an : (NANCH - 1);

        const float *cp, *pp;
        if (n < N20) {
            cp = c20 + ((size_t)b * N20 + n) * NUM_CLASSES;
            pp = p20 + (size_t)b * N20 + n;
        } else if (n < N20 + N40) {
            int a = n - N20;
            cp = c40 + ((size_t)b * N40 + a) * NUM_CLASSES;
            pp = p40 + (size_t)b * N40 + a;
        } else {
            int a = n - N20 - N40;
            cp = c80 + ((size_t)b * N80 + a) * NUM_CLASSES;
            pp = p80 + (size_t)b * N80 + a;
        }

        const float4* c4 = (const float4*)cp;
        float p = *pp;
        float4 v[20];
#pragma unroll
        for (int k = 0; k < 20; k++) v[k] = c4[k];
        __builtin_amdgcn_sched_barrier(0);   // all 20 loads in flight

        float best = -INFINITY;
        int bi = 0;
#pragma unroll
        for (int k = 0; k < 20; k++) {
            int basei = k * 4;
            if (v[k].x > best) { best = v[k].x; bi = basei; }
            if (v[k].y > best) { best = v[k].y; bi = basei + 1; }
            if (v[k].z > best) { best = v[k].z; bi = basei + 2; }
            if (v[k].w > best) { best = v[k].w; bi = basei + 3; }
        }

        float s = __fmul_rn(p, (float)bi);       // exact fp32, matches np
        float sval = (s > SCORE_THR) ? s : NEGV;
        if (valid_an) scores[(size_t)b * NANCH + an] = sval;

        bool pred = valid_an && (s >= THR_LIST);
        ull mask = __ballot(pred);
        if (mask != 0ull) {
            int leader = (int)(__ffsll(mask) - 1);
            unsigned basep = 0;
            if (lane == leader) basep = atomicAdd(&cand_cnt[b], (unsigned)__popcll(mask));
            basep = __shfl(basep, leader);
            if (pred) {
                unsigned pos = basep + (unsigned)__popcll(mask & ((1ull << lane) - 1));
                if (pos < (unsigned)CAP)
                    cand_keys[(size_t)b * CAP + pos] =
                        ((ull)__float_as_uint(s) << 32)
                      | (ull)(0xFFFFFFFFu - (unsigned)an);
            }
        }
        __syncthreads();
        if (t == 0) { __threadfence(); atomicAdd(&done_cnt[b], 1u); }
        return;
    }

    // ------------------------------- consumer -----------------------------
    const int b = blk - BATCH * NPB;

    if (t == 0) {
        while (__hip_atomic_load(&done_cnt[b], __ATOMIC_RELAXED,
                                 __HIP_MEMORY_SCOPE_AGENT) < (unsigned)NPB)
            __builtin_amdgcn_s_sleep(16);
        __threadfence();                 // acquire
        sh_V = 0; sh_pcnt = 0u;
    }
    for (int i = t; i < NHBIN; i += 256) hist[i] = 0u;
    __syncthreads();

    const unsigned cnt_raw = __hip_atomic_load(&cand_cnt[b], __ATOMIC_RELAXED,
                                               __HIP_MEMORY_SCOPE_AGENT);
    const bool use_list = (cnt_raw <= (unsigned)CAP);
    const int cnt = use_list ? (int)cnt_raw : 0;
    const int nR = min(cnt, RMAX);
    const unsigned need = (unsigned)nR;

    // load my 4 slots, bins, histogram
    ull k4[4]; int bin4[4];
#pragma unroll
    for (int i = 0; i < 4; i++) {
        const int c = t + i * 256;
        k4[i] = 0ull; bin4[i] = -1;
        if (c < cnt) {
            ull k = cand_keys[(size_t)b * CAP + c];
            k4[i] = k;
            skeys[c] = k;
            unsigned sb = (unsigned)(k >> 32);           // in [0x42800000,0x43000000)
            bin4[i] = min((int)((sb - 0x42800000u) >> 13), NHBIN - 1);
        }
    }
    __syncthreads();
#pragma unroll
    for (int i = 0; i < 4; i++) if (bin4[i] >= 0) atomicAdd(&hist[bin4[i]], 1u);
    __syncthreads();

    // wave 0: suffix-sum over 1024 bins; T = max b with suffix[b] >= need
    if (t < 64) {
        unsigned h[16], sfx[16];
        const int basei = t * 16;
#pragma unroll
        for (int k = 0; k < 16; k++) h[k] = hist[basei + k];
        unsigned run = 0;
#pragma unroll
        for (int k = 15; k >= 0; k--) { run += h[k]; sfx[k] = run; }
        unsigned s = run;
#pragma unroll
        for (int d = 1; d < 64; d <<= 1) {
            unsigned vv = __shfl_down(s, d);
            if (t + d < 64) s += vv;
        }
        const unsigned above = s - run;
        int bestb = -1;
#pragma unroll
        for (int k = 0; k < 16; k++)
            if (sfx[k] + above >= need) bestb = basei + k;   // ascending keeps max
#pragma unroll
        for (int d = 32; d > 0; d >>= 1) {
            int o = __shfl_down(bestb, d);
            if (t + d < 64) bestb = max(bestb, o);
        }
        if (t == 0) sh_T = max(bestb, 0);
    }
    __syncthreads();
    const int T = sh_T;

    // compact participants (4 wave-aggregated rounds)
#pragma unroll
    for (int i = 0; i < 4; i++) {
        bool part = (bin4[i] >= T);
        ull mask = __ballot(part);
        if (mask != 0ull) {
            int leader = (int)(__ffsll(mask) - 1);
            unsigned basep = 0;
            if (lane == leader) basep = atomicAdd(&sh_pcnt, (unsigned)__popcll(mask));
            basep = __shfl(basep, leader);
            if (part) {
                unsigned pos = basep + (unsigned)__popcll(mask & ((1ull << lane) - 1));
                if (pos < (unsigned)PKCAP) pk[pos] = k4[i];
            }
        }
    }
    __syncthreads();
    const int m = (int)sh_pcnt;

    if (m <= PKCAP) {
        // prefetch boxes for my 2 participants (in flight during rank)
        ull kA = 0ull, kB = 0ull;
        float4 bA = make_float4(0.f,0.f,0.f,0.f), bB = bA;
        const bool hasA = (t < m), hasB = (t + 256 < m);
        if (hasA) { kA = pk[t];        bA = load_box(b, key_idx(kA), b20, b40, b80); }
        if (hasB) { kB = pk[t + 256];  bB = load_box(b, key_idx(kB), b20, b40, b80); }
        // rank (wave-uniform broadcast reads)
        int rA = 0, rB = 0;
#pragma unroll 8
        for (int j = 0; j < m; j++) {
            ull kj = pk[j];
            rA += (kj > kA) ? 1 : 0;
            rB += (kj > kB) ? 1 : 0;
        }
        if (hasA && rA < RMAX) { srt_key[rA] = kA; bbox[rA] = bA; }
        if (hasB && rB < RMAX) { srt_key[rB] = kB; bbox[rB] = bB; }
        __syncthreads();
    } else {
        // guard: full rank of my 4 slots over all cnt keys
        int r4[4] = {0, 0, 0, 0};
        for (int j = 0; j < cnt; j++) {
            ull kj = skeys[j];
#pragma unroll
            for (int i = 0; i < 4; i++) r4[i] += (kj > k4[i]) ? 1 : 0;
        }
#pragma unroll
        for (int i = 0; i < 4; i++) {
            const int c = t + i * 256;
            if (c < cnt && r4[i] < RMAX) srt_key[r4[i]] = k4[i];
        }
        __syncthreads();
        if (t < nR) bbox[t] = load_box(b, key_idx(srt_key[t]), b20, b40, b80);
        __syncthreads();
    }

    // suppression matrix: M[row][cw] bit j = (rank cw*64+j suppresses row).
    // cw is uniform per round -> inner bbox read is a free LDS broadcast.
#pragma unroll
    for (int cw = 0; cw < 3; cw++) {
        if (t < RMAX) {
            const int row = t;
            ull w = 0ull;
            if (row < nR && cw * 64 < row) {
                const float4 B = bbox[row];
                const float aB = box_area(B);
                const int jmax = min(64, row - cw * 64);
                const float4* src = &bbox[cw * 64];
                for (int j = 0; j < jmax; j++) {
                    const float4 C = src[j];
                    w |= ((ull)iou_gt(C, box_area(C), B, aB)) << j;
                }
            }
            M[row][cw] = w;
        }
    }
    __syncthreads();

    // greedy resolution: wave 0, accepted-set in registers (pure VALU)
    int v = 0;
    if (t < 64) {
        ull A0 = 0, A1 = 0, A2 = 0;
        for (int rg = 0; rg < 3 && v < 100; rg++) {
            const int rr = rg * 64 + t;
            const bool valid = (rr < nR);
            ull w0 = 0, w1 = 0, w2 = 0;
            if (valid) { w0 = M[rr][0]; w1 = M[rr][1]; w2 = M[rr][2]; }
            const ull mw = (rg == 0) ? w0 : (rg == 1) ? w1 : w2;
            const bool supE = !valid ||
                (((w0 & A0) | (w1 & A1) | (w2 & A2)) != 0ull);
            ull alive = __ballot(!supE);
            while (alive != 0ull && v < 100) {
                int c = (int)(__ffsll(alive) - 1);
                ull supc = __ballot((bool)((mw >> c) & 1ull));
                alive &= ~(supc | (1ull << c));
                if (rg == 0) A0 |= 1ull << c;
                else if (rg == 1) A1 |= 1ull << c;
                else A2 |= 1ull << c;
                if (t == c) {
                    const float4 B = bbox[rr];
                    float* rowp = out + ((size_t)b * 100 + v) * 6;
                    rowp[0] = fminf(fmaxf(B.x, 0.f), 1.f);
                    rowp[1] = fminf(fmaxf(B.y, 0.f), 1.f);
                    rowp[2] = fminf(fmaxf(B.z, 0.f), 1.f);
                    rowp[3] = fminf(fmaxf(B.w, 0.f), 1.f);
                    rowp[4] = __uint_as_float((unsigned)(srt_key[rr] >> 32));
                    rowp[5] = 0.f;
                }
                v++;
            }
        }
        if (t == 0) sh_V = v;
    }
    __syncthreads();

    // ------- exact fallback: reference-style greedy (never taken here) -----
    const bool need_fb = (!use_list) || (sh_V < 100 && cnt > nR);
    if (need_fb) {
        float* scb = scores + (size_t)b * NANCH;
        int v2 = 0;
        for (int k = 0; k < 100; k++) {
            ull bestk = 0ull;
            for (int i = t; i < NANCH; i += 256) {
                float sv = scb[i];
                unsigned u = __float_as_uint(sv);
                u ^= (u & 0x80000000u) ? 0xFFFFFFFFu : 0x80000000u;
                ull key = ((ull)u << 32) | (ull)(0xFFFFFFFFu - (unsigned)i);
                if (key > bestk) bestk = key;
            }
            red[t] = bestk;
            __syncthreads();
            for (int ss = 128; ss > 0; ss >>= 1) {
                if (t < ss && red[t + ss] > red[t]) red[t] = red[t + ss];
                __syncthreads();
            }
            ull bk = red[0];
            __syncthreads();
            unsigned u = (unsigned)(bk >> 32);
            u ^= (u & 0x80000000u) ? 0x80000000u : 0xFFFFFFFFu;
            float s = __uint_as_float(u);
            int idx = (int)(0xFFFFFFFFu - (unsigned)(bk & 0xFFFFFFFFull));
            if (!(s > NEGV * 0.5f)) break;                  // wave-uniform
            float4 B = load_box(b, idx, b20, b40, b80);
            float aB = box_area(B);
            for (int i = t; i < NANCH; i += 256) {
                float sv = scb[i];
                if (sv > NEGV * 0.5f) {
                    float4 C = load_box(b, i, b20, b40, b80);
                    if (iou_gt(B, aB, C, box_area(C))) scb[i] = NEGV;
                }
            }
            if (t == 0) {
                scb[idx] = NEGV;
                float* rowp = out + ((size_t)b * 100 + k) * 6;
                rowp[0] = fminf(fmaxf(B.x, 0.f), 1.f);
                rowp[1] = fminf(fmaxf(B.y, 0.f), 1.f);
                rowp[2] = fminf(fmaxf(B.z, 0.f), 1.f);
                rowp[3] = fminf(fmaxf(B.w, 0.f), 1.f);
                rowp[4] = s;
                rowp[5] = 0.f;
            }
            v2++;
            __syncthreads();
        }
        __syncthreads();
        if (t == 0) sh_V = v2;
        __syncthreads();
    }

    const int V = sh_V;
    for (int i = V * 6 + t; i < 600; i += 256) out[(size_t)b * 600 + i] = 0.f;
    if (t == 0) out[4800 + b] = (float)V;
}

extern "C" void kernel_launch(void* const* d_in, const int* in_sizes, int n_in,
                              void* d_out, int out_size, void* d_ws, size_t ws_size,
                              hipStream_t stream) {
    const float* b20 = (const float*)d_in[0];
    const float* p20 = (const float*)d_in[1];
    const float* c20 = (const float*)d_in[2];
    const float* b40 = (const float*)d_in[3];
    const float* p40 = (const float*)d_in[4];
    const float* c40 = (const float*)d_in[5];
    const float* b80 = (const float*)d_in[6];
    const float* p80 = (const float*)d_in[7];
    const float* c80 = (const float*)d_in[8];

    float*    scores   = (float*)d_ws;                            // 806400 B
    unsigned* cand_cnt = (unsigned*)((char*)d_ws + 806400);       // 32 B
    unsigned* done_cnt = cand_cnt + BATCH;                        // 32 B
    ull*      cand_keys = (ull*)((char*)d_ws + 806464);           // 8*CAP*8 B

    hipMemsetAsync(cand_cnt, 0, 2 * BATCH * sizeof(unsigned), stream);

    fused_kernel<<<BATCH * NPB + BATCH, 256, 0, stream>>>(
        b20, p20, c20, b40, p40, c40, b80, p80, c80,
        scores, cand_cnt, done_cnt, cand_keys, (float*)d_out);
}

// Round 10
// 152.935 us; speedup vs baseline: 1.3055x; 1.3055x over previous
//
#include <hip/hip_runtime.h>
#include <hip/hip_bf16.h>

#define NUM_CLASSES 80
#define BATCH 8
#define N20 1200
#define N40 4800
#define N80 19200
#define NANCH 25200
#define NEGV  -1000000000.0f
#define SCORE_THR 0.25f
#define CAP 2048            // candidate capacity (expected ~490/batch)
#define RMAX 192            // ranks materialized in the suppression matrix
#define PKCAP 512           // prefiltered participant capacity
#define NHBIN 1024          // histogram bins over the [64,128) octave
#define THR_LIST 64.0f      // candidate threshold (exact float)

typedef unsigned long long ull;

// ---------------------------------------------------------------------------
// Kernel 1: class argmax + score only. __launch_bounds__(256,3) grants ~170
// VGPRs so all 20 dwordx4 loads stay in flight (the R9 post-mortem showed a
// 44-VGPR budget serializes them). No candidate append — nms scans scores.
// ---------------------------------------------------------------------------
__global__ __launch_bounds__(256, 3) void score_kernel(
        const float* __restrict__ p20, const float* __restrict__ c20,
        const float* __restrict__ p40, const float* __restrict__ c40,
        const float* __restrict__ p80, const float* __restrict__ c80,
        float* __restrict__ scores) {
    const int t = threadIdx.x;
    const int b = blockIdx.y;
    const int an = blockIdx.x * 256 + t;
    const bool valid_an = (an < NANCH);
    const int n = valid_an ? an : (NANCH - 1);

    const float *cp, *pp;
    if (n < N20) {
        cp = c20 + ((size_t)b * N20 + n) * NUM_CLASSES;
        pp = p20 + (size_t)b * N20 + n;
    } else if (n < N20 + N40) {
        int a = n - N20;
        cp = c40 + ((size_t)b * N40 + a) * NUM_CLASSES;
        pp = p40 + (size_t)b * N40 + a;
    } else {
        int a = n - N20 - N40;
        cp = c80 + ((size_t)b * N80 + a) * NUM_CLASSES;
        pp = p80 + (size_t)b * N80 + a;
    }

    const float4* c4 = (const float4*)cp;
    float p = *pp;
    float4 v[20];
#pragma unroll
    for (int k = 0; k < 20; k++) v[k] = c4[k];
    __builtin_amdgcn_sched_barrier(0);   // keep all 20 loads above the argmax

    float best = -INFINITY;
    int bi = 0;
#pragma unroll
    for (int k = 0; k < 20; k++) {
        int basei = k * 4;
        if (v[k].x > best) { best = v[k].x; bi = basei; }
        if (v[k].y > best) { best = v[k].y; bi = basei + 1; }
        if (v[k].z > best) { best = v[k].z; bi = basei + 2; }
        if (v[k].w > best) { best = v[k].w; bi = basei + 3; }
    }

    float s = __fmul_rn(p, (float)bi);           // exact fp32, matches np
    float sval = (s > SCORE_THR) ? s : NEGV;
    if (valid_an) scores[(size_t)b * NANCH + an] = sval;   // coalesced
}

// exact IEEE fp32 (no FMA contraction) "IoU > 0.5" — matches numpy ref
__device__ __forceinline__ bool iou_gt(const float4 A, float areaA, const float4 Bx, float areaB) {
    float ih = fmaxf(__fsub_rn(fminf(A.z, Bx.z), fmaxf(A.x, Bx.x)), 0.0f);
    float iw = fmaxf(__fsub_rn(fminf(A.w, Bx.w), fmaxf(A.y, Bx.y)), 0.0f);
    float inter = __fmul_rn(ih, iw);
    float uni = __fsub_rn(__fadd_rn(areaA, areaB), inter);
    if (!(uni > 0.0f)) return false;
    return __fdiv_rn(inter, uni) > 0.5f;
}

__device__ __forceinline__ float4 load_box(int b, int n,
        const float* b20, const float* b40, const float* b80) {
    if (n < N20)       return ((const float4*)b20)[(size_t)b * N20 + n];
    if (n < N20 + N40) return ((const float4*)b40)[(size_t)b * N40 + (n - N20)];
    return ((const float4*)b80)[(size_t)b * N80 + (n - N20 - N40)];
}

__device__ __forceinline__ float box_area(const float4 B) {
    return __fmul_rn(__fsub_rn(B.z, B.x), __fsub_rn(B.w, B.y));
}

__device__ __forceinline__ int key_idx(ull k) {
    return (int)(0xFFFFFFFFu - (unsigned)(k & 0xFFFFFFFFull));
}

// ---------------------------------------------------------------------------
// Kernel 2: exact greedy NMS. Scans scores directly (float4), building the
// candidate list + histogram in one pass (no global key round-trip, no
// memset dispatch). Then: threshold -> participants -> rank -> RMAX=192
// suppression matrix -> bitmap resolve. Exact guard/fallback preserved.
// ---------------------------------------------------------------------------
__global__ __launch_bounds__(1024) void nms_kernel(
        float* __restrict__ scores,
        const float* __restrict__ b20, const float* __restrict__ b40,
        const float* __restrict__ b80, float* __restrict__ out) {
    __shared__ ull skeys[CAP];          // 16 KB
    __shared__ ull pk[PKCAP];           // 4 KB participants
    __shared__ unsigned hist[NHBIN];    // 4 KB
    __shared__ int prt[PKCAP][5];       // 10 KB (bank-padded rank partials)
    __shared__ ull srt_key[RMAX];       // 1.5 KB
    __shared__ float4 bbox[RMAX];       // 3 KB
    __shared__ ull M[RMAX][3];          // 4.5 KB
    __shared__ ull red[1024];           // 8 KB (fallback argmax reduce)
    __shared__ int sh_V, sh_T;
    __shared__ unsigned sh_cnt, sh_pcnt;

    const int t = threadIdx.x;
    const int lane = t & 63;
    const int b = blockIdx.x;

    hist[t] = 0u;                       // NHBIN == blockDim == 1024
    if (t == 0) { sh_V = 0; sh_cnt = 0u; sh_pcnt = 0u; }
    __syncthreads();

    // ---- scan scores: compact candidates (s >= 64) + histogram, one pass --
    const float4* sc4 = (const float4*)(scores + (size_t)b * NANCH);
#pragma unroll
    for (int it = 0; it < 7; it++) {            // 7*1024 >= 6300 (uniform trips)
        const int i = t + it * 1024;
        const bool in = (i < NANCH / 4);
        float4 s4 = in ? sc4[i] : make_float4(NEGV, NEGV, NEGV, NEGV);
        const float sv[4] = {s4.x, s4.y, s4.z, s4.w};
#pragma unroll
        for (int c = 0; c < 4; c++) {
            const bool pred = in && (sv[c] >= THR_LIST);
            ull mask = __ballot(pred);
            if (mask != 0ull) {
                int leader = (int)(__ffsll(mask) - 1);
                unsigned basep = 0;
                if (lane == leader) basep = atomicAdd(&sh_cnt, (unsigned)__popcll(mask));
                basep = __shfl(basep, leader);
                if (pred) {
                    const unsigned sb = __float_as_uint(sv[c]);
                    const unsigned an = (unsigned)(i * 4 + c);
                    unsigned pos = basep + (unsigned)__popcll(mask & ((1ull << lane) - 1));
                    if (pos < (unsigned)CAP)
                        skeys[pos] = ((ull)sb << 32) | (ull)(0xFFFFFFFFu - an);
                    atomicAdd(&hist[min((int)((sb - 0x42800000u) >> 13), NHBIN - 1)], 1u);
                }
            }
        }
    }
    __syncthreads();

    const int cnt = (int)sh_cnt;
    const bool use_list = (cnt <= CAP);
    const int nR = use_list ? min(cnt, RMAX) : 0;
    const unsigned need = (unsigned)nR;

    if (use_list) {
        // wave 0: suffix-sum over 1024 bins; T = max bin with suffix >= need
        if (t < 64) {
            unsigned h[16], sfx[16];
            const int basei = t * 16;
#pragma unroll
            for (int k = 0; k < 16; k++) h[k] = hist[basei + k];
            unsigned run = 0;
#pragma unroll
            for (int k = 15; k >= 0; k--) { run += h[k]; sfx[k] = run; }
            unsigned s = run;
#pragma unroll
            for (int d = 1; d < 64; d <<= 1) {
                unsigned vv = __shfl_down(s, d);
                if (t + d < 64) s += vv;
            }
            const unsigned above = s - run;
            int bestb = -1;
#pragma unroll
            for (int k = 0; k < 16; k++)
                if (sfx[k] + above >= need) bestb = basei + k;   // ascending keeps max
#pragma unroll
            for (int d = 32; d > 0; d >>= 1) {
                int o = __shfl_down(bestb, d);
                if (t + d < 64) bestb = max(bestb, o);
            }
            if (t == 0) sh_T = max(bestb, 0);
        }
        __syncthreads();
        const int T = sh_T;

        // compact participants (2 wave-aggregated rounds over skeys)
#pragma unroll
        for (int h = 0; h < 2; h++) {
            const int c = t + h * 1024;
            bool part = false;
            ull k = 0ull;
            if (c < cnt) {
                k = skeys[c];
                int bin = min((int)(((unsigned)(k >> 32) - 0x42800000u) >> 13), NHBIN - 1);
                part = (bin >= T);
            }
            ull mask = __ballot(part);
            if (mask != 0ull) {
                int leader = (int)(__ffsll(mask) - 1);
                unsigned basep = 0;
                if (lane == leader) basep = atomicAdd(&sh_pcnt, (unsigned)__popcll(mask));
                basep = __shfl(basep, leader);
                if (part) {
                    unsigned pos = basep + (unsigned)__popcll(mask & ((1ull << lane) - 1));
                    if (pos < (unsigned)PKCAP) pk[pos] = k;
                }
            }
        }
        __syncthreads();
        const int m = (int)sh_pcnt;

        if (m <= PKCAP) {
            // prefetch my participant's box (in flight during rank)
            ull kmy = 0ull;
            float4 bmy = make_float4(0.f, 0.f, 0.f, 0.f);
            if (t < m) {
                kmy = pk[t];
                bmy = load_box(b, key_idx(kmy), b20, b40, b80);
            }
            // rank: thread (q,u) ranks pk[u], pk[u+256] over j-quarter q
            const int q = t >> 8, u = t & 255;
            const ull kA = (u < m) ? pk[u] : 0ull;
            const ull kB = (u + 256 < m) ? pk[u + 256] : 0ull;
            const int Q = (m + 3) >> 2;
            const int j0 = q * Q, j1 = min(m, j0 + Q);
            int rA = 0, rB = 0;
#pragma unroll 8
            for (int j = j0; j < j1; j++) {
                ull kj = pk[j];
                rA += (kj > kA) ? 1 : 0;
                rB += (kj > kB) ? 1 : 0;
            }
            prt[u][q] = rA;
            prt[u + 256][q] = rB;
            __syncthreads();
            if (t < m) {
                int r = prt[t][0] + prt[t][1] + prt[t][2] + prt[t][3];
                if (r < RMAX) { srt_key[r] = kmy; bbox[r] = bmy; }
            }
            __syncthreads();
        } else {
            // guard: full rank of my 2 slots over all cnt keys
            ull kA = (t < cnt) ? skeys[t] : 0ull;
            ull kB = (t + 1024 < cnt) ? skeys[t + 1024] : 0ull;
            int rA = 0, rB = 0;
            for (int j = 0; j < cnt; j++) {
                ull kj = skeys[j];
                rA += (kj > kA) ? 1 : 0;
                rB += (kj > kB) ? 1 : 0;
            }
            if (t < cnt && rA < RMAX) srt_key[rA] = kA;
            if (t + 1024 < cnt && rB < RMAX) srt_key[rB] = kB;
            __syncthreads();
            if (t < nR) bbox[t] = load_box(b, key_idx(srt_key[t]), b20, b40, b80);
            __syncthreads();
        }

        // suppression matrix: M[row][cw] bit j = (rank cw*64+j suppresses row)
        {
            const int row = t >> 2, cw = t & 3;
            if (row < RMAX && cw < 3) {
                ull w = 0ull;
                if (row < nR && cw * 64 < row) {
                    const float4 B = bbox[row];
                    const float aB = box_area(B);
                    const int jmax = min(64, row - cw * 64);
                    const float4* src = &bbox[cw * 64];
                    for (int j = 0; j < jmax; j++) {
                        const float4 C = src[j];
                        w |= ((ull)iou_gt(C, box_area(C), B, aB)) << j;
                    }
                }
                M[row][cw] = w;
            }
        }
        __syncthreads();

        // greedy resolution: wave 0, accepted-set in registers (pure VALU)
        int v = 0;
        if (t < 64) {
            ull A0 = 0, A1 = 0, A2 = 0;
            for (int rg = 0; rg < 3 && v < 100; rg++) {
                const int rr = rg * 64 + t;
                const bool valid = (rr < nR);
                ull w0 = 0, w1 = 0, w2 = 0;
                if (valid) { w0 = M[rr][0]; w1 = M[rr][1]; w2 = M[rr][2]; }
                const ull mw = (rg == 0) ? w0 : (rg == 1) ? w1 : w2;
                const bool supE = !valid ||
                    (((w0 & A0) | (w1 & A1) | (w2 & A2)) != 0ull);
                ull alive = __ballot(!supE);
                while (alive != 0ull && v < 100) {
                    int c = (int)(__ffsll(alive) - 1);
                    ull supc = __ballot((bool)((mw >> c) & 1ull));
                    alive &= ~(supc | (1ull << c));
                    if (rg == 0) A0 |= 1ull << c;
                    else if (rg == 1) A1 |= 1ull << c;
                    else A2 |= 1ull << c;
                    if (t == c) {
                        const float4 B = bbox[rr];
                        float* rowp = out + ((size_t)b * 100 + v) * 6;
                        rowp[0] = fminf(fmaxf(B.x, 0.f), 1.f);
                        rowp[1] = fminf(fmaxf(B.y, 0.f), 1.f);
                        rowp[2] = fminf(fmaxf(B.z, 0.f), 1.f);
                        rowp[3] = fminf(fmaxf(B.w, 0.f), 1.f);
                        rowp[4] = __uint_as_float((unsigned)(srt_key[rr] >> 32));
                        rowp[5] = 0.f;
                    }
                    v++;
                }
            }
            if (t == 0) sh_V = v;
        }
        __syncthreads();
    }

    // ------- exact fallback: reference-style greedy (never taken here) -----
    const bool need_fb = (!use_list) || (sh_V < 100 && cnt > nR);
    if (need_fb) {
        float* scb = scores + (size_t)b * NANCH;
        int v2 = 0;
        for (int k = 0; k < 100; k++) {
            ull bestk = 0ull;
            for (int i = t; i < NANCH; i += 1024) {
                float sv = scb[i];
                unsigned u = __float_as_uint(sv);
                u ^= (u & 0x80000000u) ? 0xFFFFFFFFu : 0x80000000u;
                ull key = ((ull)u << 32) | (ull)(0xFFFFFFFFu - (unsigned)i);
                if (key > bestk) bestk = key;
            }
            red[t] = bestk;
            __syncthreads();
            for (int ss = 512; ss > 0; ss >>= 1) {
                if (t < ss && red[t + ss] > red[t]) red[t] = red[t + ss];
                __syncthreads();
            }
            ull bk = red[0];
            __syncthreads();
            unsigned u = (unsigned)(bk >> 32);
            u ^= (u & 0x80000000u) ? 0x80000000u : 0xFFFFFFFFu;
            float s = __uint_as_float(u);
            int idx = (int)(0xFFFFFFFFu - (unsigned)(bk & 0xFFFFFFFFull));
            if (!(s > NEGV * 0.5f)) break;                  // wave-uniform
            float4 B = load_box(b, idx, b20, b40, b80);
            float aB = box_area(B);
            for (int i = t; i < NANCH; i += 1024) {
                float sv = scb[i];
                if (sv > NEGV * 0.5f) {
                    float4 C = load_box(b, i, b20, b40, b80);
                    if (iou_gt(B, aB, C, box_area(C))) scb[i] = NEGV;
                }
            }
            if (t == 0) {
                scb[idx] = NEGV;
                float* rowp = out + ((size_t)b * 100 + k) * 6;
                rowp[0] = fminf(fmaxf(B.x, 0.f), 1.f);
                rowp[1] = fminf(fmaxf(B.y, 0.f), 1.f);
                rowp[2] = fminf(fmaxf(B.z, 0.f), 1.f);
                rowp[3] = fminf(fmaxf(B.w, 0.f), 1.f);
                rowp[4] = s;
                rowp[5] = 0.f;
            }
            v2++;
            __syncthreads();
        }
        __syncthreads();
        if (t == 0) sh_V = v2;
        __syncthreads();
    }

    const int V = sh_V;
    for (int i = V * 6 + t; i < 600; i += 1024) out[(size_t)b * 600 + i] = 0.f;
    if (t == 0) out[4800 + b] = (float)V;
}

extern "C" void kernel_launch(void* const* d_in, const int* in_sizes, int n_in,
                              void* d_out, int out_size, void* d_ws, size_t ws_size,
                              hipStream_t stream) {
    const float* b20 = (const float*)d_in[0];
    const float* p20 = (const float*)d_in[1];
    const float* c20 = (const float*)d_in[2];
    const float* b40 = (const float*)d_in[3];
    const float* p40 = (const float*)d_in[4];
    const float* c40 = (const float*)d_in[5];
    const float* b80 = (const float*)d_in[6];
    const float* p80 = (const float*)d_in[7];
    const float* c80 = (const float*)d_in[8];

    float* scores = (float*)d_ws;                 // 806400 B

    dim3 sgrid((NANCH + 255) / 256, BATCH);
    score_kernel<<<sgrid, 256, 0, stream>>>(
        p20, c20, p40, c40, p80, c80, scores);

    nms_kernel<<<BATCH, 1024, 0, stream>>>(
        scores, b20, b40, b80, (float*)d_out);
}

// Round 11
// 150.841 us; speedup vs baseline: 1.3237x; 1.0139x over previous
//
#include <hip/hip_runtime.h>
#include <hip/hip_bf16.h>

#define NUM_CLASSES 80
#define BATCH 8
#define N20 1200
#define N40 4800
#define N80 19200
#define NANCH 25200
#define NEGV  -1000000000.0f
#define SCORE_THR 0.25f
#define CAP 2048            // candidate capacity (expected ~510/batch)
#define RMAX 192            // ranks materialized in the suppression matrix
#define PKCAP 512           // prefiltered participant capacity
#define NHBIN 1024          // histogram bins over the [64,128) octave
#define THR_LIST 64.0f      // candidate threshold (exact float)

typedef unsigned long long ull;

// ---------------------------------------------------------------------------
// Kernel 1: class argmax + score only (R10-proven). __launch_bounds__(256,3)
// grants ~170 VGPRs so all 20 dwordx4 loads stay in flight.
// ---------------------------------------------------------------------------
__global__ __launch_bounds__(256, 3) void score_kernel(
        const float* __restrict__ p20, const float* __restrict__ c20,
        const float* __restrict__ p40, const float* __restrict__ c40,
        const float* __restrict__ p80, const float* __restrict__ c80,
        float* __restrict__ scores) {
    const int t = threadIdx.x;
    const int b = blockIdx.y;
    const int an = blockIdx.x * 256 + t;
    const bool valid_an = (an < NANCH);
    const int n = valid_an ? an : (NANCH - 1);

    const float *cp, *pp;
    if (n < N20) {
        cp = c20 + ((size_t)b * N20 + n) * NUM_CLASSES;
        pp = p20 + (size_t)b * N20 + n;
    } else if (n < N20 + N40) {
        int a = n - N20;
        cp = c40 + ((size_t)b * N40 + a) * NUM_CLASSES;
        pp = p40 + (size_t)b * N40 + a;
    } else {
        int a = n - N20 - N40;
        cp = c80 + ((size_t)b * N80 + a) * NUM_CLASSES;
        pp = p80 + (size_t)b * N80 + a;
    }

    const float4* c4 = (const float4*)cp;
    float p = *pp;
    float4 v[20];
#pragma unroll
    for (int k = 0; k < 20; k++) v[k] = c4[k];
    __builtin_amdgcn_sched_barrier(0);   // keep all 20 loads above the argmax

    float best = -INFINITY;
    int bi = 0;
#pragma unroll
    for (int k = 0; k < 20; k++) {
        int basei = k * 4;
        if (v[k].x > best) { best = v[k].x; bi = basei; }
        if (v[k].y > best) { best = v[k].y; bi = basei + 1; }
        if (v[k].z > best) { best = v[k].z; bi = basei + 2; }
        if (v[k].w > best) { best = v[k].w; bi = basei + 3; }
    }

    float s = __fmul_rn(p, (float)bi);           // exact fp32, matches np
    float sval = (s > SCORE_THR) ? s : NEGV;
    if (valid_an) scores[(size_t)b * NANCH + an] = sval;   // coalesced
}

// exact IEEE fp32 (no FMA contraction) "IoU > 0.5" — matches numpy ref
__device__ __forceinline__ bool iou_gt(const float4 A, float areaA, const float4 Bx, float areaB) {
    float ih = fmaxf(__fsub_rn(fminf(A.z, Bx.z), fmaxf(A.x, Bx.x)), 0.0f);
    float iw = fmaxf(__fsub_rn(fminf(A.w, Bx.w), fmaxf(A.y, Bx.y)), 0.0f);
    float inter = __fmul_rn(ih, iw);
    float uni = __fsub_rn(__fadd_rn(areaA, areaB), inter);
    if (!(uni > 0.0f)) return false;
    return __fdiv_rn(inter, uni) > 0.5f;
}

// Same exact predicate with a division screen: if 2*inter < uni*(1-2^-23)
// then r = inter/uni < 0.5*(1-2^-23)*(1+2^-24) < 0.5, so q_rn(r) <= 0.5 and
// the answer is provably false without dividing. Borderline pairs (rare)
// take the exact __fdiv_rn path — bit-identical decisions to numpy.
__device__ __forceinline__ bool iou_gt_fast(const float4 A, float areaA, const float4 Bx, float areaB) {
    float ih = fmaxf(__fsub_rn(fminf(A.z, Bx.z), fmaxf(A.x, Bx.x)), 0.0f);
    float iw = fmaxf(__fsub_rn(fminf(A.w, Bx.w), fmaxf(A.y, Bx.y)), 0.0f);
    float inter = __fmul_rn(ih, iw);
    float uni = __fsub_rn(__fadd_rn(areaA, areaB), inter);
    if (!(uni > 0.0f)) return false;
    if (__fmul_rn(2.0f, inter) < __fmul_rn(uni, 0.99999988f)) return false;
    return __fdiv_rn(inter, uni) > 0.5f;
}

__device__ __forceinline__ float4 load_box(int b, int n,
        const float* b20, const float* b40, const float* b80) {
    if (n < N20)       return ((const float4*)b20)[(size_t)b * N20 + n];
    if (n < N20 + N40) return ((const float4*)b40)[(size_t)b * N40 + (n - N20)];
    return ((const float4*)b80)[(size_t)b * N80 + (n - N20 - N40)];
}

__device__ __forceinline__ float box_area(const float4 B) {
    return __fmul_rn(__fsub_rn(B.z, B.x), __fsub_rn(B.w, B.y));
}

__device__ __forceinline__ int key_idx(ull k) {
    return (int)(0xFFFFFFFFu - (unsigned)(k & 0xFFFFFFFFull));
}

// ---------------------------------------------------------------------------
// Kernel 2: exact greedy NMS (R10 pipeline). Changes vs R10: matrix build
// reads 4 bank-offset box copies (conflict-free, R8-proven) and uses the
// screened IoU predicate (div only on borderline pairs).
// ---------------------------------------------------------------------------
__global__ __launch_bounds__(1024) void nms_kernel(
        float* __restrict__ scores,
        const float* __restrict__ b20, const float* __restrict__ b40,
        const float* __restrict__ b80, float* __restrict__ out) {
    __shared__ ull skeys[CAP];              // 16 KB
    __shared__ ull pk[PKCAP];               // 4 KB participants
    __shared__ unsigned hist[NHBIN];        // 4 KB
    __shared__ int prt[PKCAP][5];           // 10 KB (bank-padded rank partials)
    __shared__ ull srt_key[RMAX];           // 1.5 KB
    __shared__ float4 bboxC[4][RMAX + 1];   // 12.4 KB (4 bank-offset copies)
    __shared__ ull M[RMAX][3];              // 4.5 KB
    __shared__ ull red[1024];               // 8 KB (fallback argmax reduce)
    __shared__ int sh_V, sh_T;
    __shared__ unsigned sh_cnt, sh_pcnt;

    const int t = threadIdx.x;
    const int lane = t & 63;
    const int b = blockIdx.x;

    hist[t] = 0u;                       // NHBIN == blockDim == 1024
    if (t == 0) { sh_V = 0; sh_cnt = 0u; sh_pcnt = 0u; }
    __syncthreads();

    // ---- scan scores: compact candidates (s >= 64) + histogram, one pass --
    const float4* sc4 = (const float4*)(scores + (size_t)b * NANCH);
#pragma unroll
    for (int it = 0; it < 7; it++) {            // 7*1024 >= 6300 (uniform trips)
        const int i = t + it * 1024;
        const bool in = (i < NANCH / 4);
        float4 s4 = in ? sc4[i] : make_float4(NEGV, NEGV, NEGV, NEGV);
        const float sv[4] = {s4.x, s4.y, s4.z, s4.w};
#pragma unroll
        for (int c = 0; c < 4; c++) {
            const bool pred = in && (sv[c] >= THR_LIST);
            ull mask = __ballot(pred);
            if (mask != 0ull) {
                int leader = (int)(__ffsll(mask) - 1);
                unsigned basep = 0;
                if (lane == leader) basep = atomicAdd(&sh_cnt, (unsigned)__popcll(mask));
                basep = __shfl(basep, leader);
                if (pred) {
                    const unsigned sb = __float_as_uint(sv[c]);
                    const unsigned an = (unsigned)(i * 4 + c);
                    unsigned pos = basep + (unsigned)__popcll(mask & ((1ull << lane) - 1));
                    if (pos < (unsigned)CAP)
                        skeys[pos] = ((ull)sb << 32) | (ull)(0xFFFFFFFFu - an);
                    atomicAdd(&hist[min((int)((sb - 0x42800000u) >> 13), NHBIN - 1)], 1u);
                }
            }
        }
    }
    __syncthreads();

    const int cnt = (int)sh_cnt;
    const bool use_list = (cnt <= CAP);
    const int nR = use_list ? min(cnt, RMAX) : 0;
    const unsigned need = (unsigned)nR;

    if (use_list) {
        // wave 0: suffix-sum over 1024 bins; T = max bin with suffix >= need
        if (t < 64) {
            unsigned h[16], sfx[16];
            const int basei = t * 16;
#pragma unroll
            for (int k = 0; k < 16; k++) h[k] = hist[basei + k];
            unsigned run = 0;
#pragma unroll
            for (int k = 15; k >= 0; k--) { run += h[k]; sfx[k] = run; }
            unsigned s = run;
#pragma unroll
            for (int d = 1; d < 64; d <<= 1) {
                unsigned vv = __shfl_down(s, d);
                if (t + d < 64) s += vv;
            }
            const unsigned above = s - run;
            int bestb = -1;
#pragma unroll
            for (int k = 0; k < 16; k++)
                if (sfx[k] + above >= need) bestb = basei + k;   // ascending keeps max
#pragma unroll
            for (int d = 32; d > 0; d >>= 1) {
                int o = __shfl_down(bestb, d);
                if (t + d < 64) bestb = max(bestb, o);
            }
            if (t == 0) sh_T = max(bestb, 0);
        }
        __syncthreads();
        const int T = sh_T;

        // compact participants (2 wave-aggregated rounds over skeys)
#pragma unroll
        for (int h = 0; h < 2; h++) {
            const int c = t + h * 1024;
            bool part = false;
            ull k = 0ull;
            if (c < cnt) {
                k = skeys[c];
                int bin = min((int)(((unsigned)(k >> 32) - 0x42800000u) >> 13), NHBIN - 1);
                part = (bin >= T);
            }
            ull mask = __ballot(part);
            if (mask != 0ull) {
                int leader = (int)(__ffsll(mask) - 1);
                unsigned basep = 0;
                if (lane == leader) basep = atomicAdd(&sh_pcnt, (unsigned)__popcll(mask));
                basep = __shfl(basep, leader);
                if (part) {
                    unsigned pos = basep + (unsigned)__popcll(mask & ((1ull << lane) - 1));
                    if (pos < (unsigned)PKCAP) pk[pos] = k;
                }
            }
        }
        __syncthreads();
        const int m = (int)sh_pcnt;

        if (m <= PKCAP) {
            // prefetch my participant's box (in flight during rank)
            ull kmy = 0ull;
            float4 bmy = make_float4(0.f, 0.f, 0.f, 0.f);
            if (t < m) {
                kmy = pk[t];
                bmy = load_box(b, key_idx(kmy), b20, b40, b80);
            }
            // rank: thread (q,u) ranks pk[u], pk[u+256] over j-quarter q
            const int q = t >> 8, u = t & 255;
            const ull kA = (u < m) ? pk[u] : 0ull;
            const ull kB = (u + 256 < m) ? pk[u + 256] : 0ull;
            const int Q = (m + 3) >> 2;
            const int j0 = q * Q, j1 = min(m, j0 + Q);
            int rA = 0, rB = 0;
#pragma unroll 8
            for (int j = j0; j < j1; j++) {
                ull kj = pk[j];
                rA += (kj > kA) ? 1 : 0;
                rB += (kj > kB) ? 1 : 0;
            }
            prt[u][q] = rA;
            prt[u + 256][q] = rB;
            __syncthreads();
            if (t < m) {
                int r = prt[t][0] + prt[t][1] + prt[t][2] + prt[t][3];
                if (r < RMAX) {
                    srt_key[r] = kmy;
#pragma unroll
                    for (int c = 0; c < 4; c++) bboxC[c][r] = bmy;
                }
            }
            __syncthreads();
        } else {
            // guard: full rank of my 2 slots over all cnt keys
            ull kA = (t < cnt) ? skeys[t] : 0ull;
            ull kB = (t + 1024 < cnt) ? skeys[t + 1024] : 0ull;
            int rA = 0, rB = 0;
            for (int j = 0; j < cnt; j++) {
                ull kj = skeys[j];
                rA += (kj > kA) ? 1 : 0;
                rB += (kj > kB) ? 1 : 0;
            }
            if (t < cnt && rA < RMAX) srt_key[rA] = kA;
            if (t + 1024 < cnt && rB < RMAX) srt_key[rB] = kB;
            __syncthreads();
            if (t < nR) {
                float4 B = load_box(b, key_idx(srt_key[t]), b20, b40, b80);
#pragma unroll
                for (int c = 0; c < 4; c++) bboxC[c][t] = B;
            }
            __syncthreads();
        }

        // suppression matrix: M[row][cw] bit j = (rank cw*64+j suppresses row)
        // bboxC bank layout: dword-bank = (4*cw + 4*j) % 32 — disjoint per cw.
        {
            const int row = t >> 2, cw = t & 3;
            if (row < RMAX && cw < 3) {
                ull w = 0ull;
                if (row < nR && cw * 64 < row) {
                    const float4 B = bboxC[cw][row];
                    const float aB = box_area(B);
                    const int jmax = min(64, row - cw * 64);
                    const float4* src = &bboxC[cw][cw * 64];
                    for (int j = 0; j < jmax; j++) {
                        const float4 C = src[j];
                        w |= ((ull)iou_gt_fast(C, box_area(C), B, aB)) << j;
                    }
                }
                M[row][cw] = w;
            }
        }
        __syncthreads();

        // greedy resolution: wave 0, accepted-set in registers (pure VALU)
        int v = 0;
        if (t < 64) {
            ull A0 = 0, A1 = 0, A2 = 0;
            for (int rg = 0; rg < 3 && v < 100; rg++) {
                const int rr = rg * 64 + t;
                const bool valid = (rr < nR);
                ull w0 = 0, w1 = 0, w2 = 0;
                if (valid) { w0 = M[rr][0]; w1 = M[rr][1]; w2 = M[rr][2]; }
                const ull mw = (rg == 0) ? w0 : (rg == 1) ? w1 : w2;
                const bool supE = !valid ||
                    (((w0 & A0) | (w1 & A1) | (w2 & A2)) != 0ull);
                ull alive = __ballot(!supE);
                while (alive != 0ull && v < 100) {
                    int c = (int)(__ffsll(alive) - 1);
                    ull supc = __ballot((bool)((mw >> c) & 1ull));
                    alive &= ~(supc | (1ull << c));
                    if (rg == 0) A0 |= 1ull << c;
                    else if (rg == 1) A1 |= 1ull << c;
                    else A2 |= 1ull << c;
                    if (t == c) {
                        const float4 B = bboxC[0][rr];
                        float* rowp = out + ((size_t)b * 100 + v) * 6;
                        rowp[0] = fminf(fmaxf(B.x, 0.f), 1.f);
                        rowp[1] = fminf(fmaxf(B.y, 0.f), 1.f);
                        rowp[2] = fminf(fmaxf(B.z, 0.f), 1.f);
                        rowp[3] = fminf(fmaxf(B.w, 0.f), 1.f);
                        rowp[4] = __uint_as_float((unsigned)(srt_key[rr] >> 32));
                        rowp[5] = 0.f;
                    }
                    v++;
                }
            }
            if (t == 0) sh_V = v;
        }
        __syncthreads();
    }

    // ------- exact fallback: reference-style greedy (never taken here) -----
    const bool need_fb = (!use_list) || (sh_V < 100 && cnt > nR);
    if (need_fb) {
        float* scb = scores + (size_t)b * NANCH;
        int v2 = 0;
        for (int k = 0; k < 100; k++) {
            ull bestk = 0ull;
            for (int i = t; i < NANCH; i += 1024) {
                float sv = scb[i];
                unsigned u = __float_as_uint(sv);
                u ^= (u & 0x80000000u) ? 0xFFFFFFFFu : 0x80000000u;
                ull key = ((ull)u << 32) | (ull)(0xFFFFFFFFu - (unsigned)i);
                if (key > bestk) bestk = key;
            }
            red[t] = bestk;
            __syncthreads();
            for (int ss = 512; ss > 0; ss >>= 1) {
                if (t < ss && red[t + ss] > red[t]) red[t] = red[t + ss];
                __syncthreads();
            }
            ull bk = red[0];
            __syncthreads();
            unsigned u = (unsigned)(bk >> 32);
            u ^= (u & 0x80000000u) ? 0x80000000u : 0xFFFFFFFFu;
            float s = __uint_as_float(u);
            int idx = (int)(0xFFFFFFFFu - (unsigned)(bk & 0xFFFFFFFFull));
            if (!(s > NEGV * 0.5f)) break;                  // wave-uniform
            float4 B = load_box(b, idx, b20, b40, b80);
            float aB = box_area(B);
            for (int i = t; i < NANCH; i += 1024) {
                float sv = scb[i];
                if (sv > NEGV * 0.5f) {
                    float4 C = load_box(b, i, b20, b40, b80);
                    if (iou_gt(B, aB, C, box_area(C))) scb[i] = NEGV;
                }
            }
            if (t == 0) {
                scb[idx] = NEGV;
                float* rowp = out + ((size_t)b * 100 + k) * 6;
                rowp[0] = fminf(fmaxf(B.x, 0.f), 1.f);
                rowp[1] = fminf(fmaxf(B.y, 0.f), 1.f);
                rowp[2] = fminf(fmaxf(B.z, 0.f), 1.f);
                rowp[3] = fminf(fmaxf(B.w, 0.f), 1.f);
                rowp[4] = s;
                rowp[5] = 0.f;
            }
            v2++;
            __syncthreads();
        }
        __syncthreads();
        if (t == 0) sh_V = v2;
        __syncthreads();
    }

    const int V = sh_V;
    for (int i = V * 6 + t; i < 600; i += 1024) out[(size_t)b * 600 + i] = 0.f;
    if (t == 0) out[4800 + b] = (float)V;
}

extern "C" void kernel_launch(void* const* d_in, const int* in_sizes, int n_in,
                              void* d_out, int out_size, void* d_ws, size_t ws_size,
                              hipStream_t stream) {
    const float* b20 = (const float*)d_in[0];
    const float* p20 = (const float*)d_in[1];
    const float* c20 = (const float*)d_in[2];
    const float* b40 = (const float*)d_in[3];
    const float* p40 = (const float*)d_in[4];
    const float* c40 = (const float*)d_in[5];
    const float* b80 = (const float*)d_in[6];
    const float* p80 = (const float*)d_in[7];
    const float* c80 = (const float*)d_in[8];

    float* scores = (float*)d_ws;                 // 806400 B

    dim3 sgrid((NANCH + 255) / 256, BATCH);
    score_kernel<<<sgrid, 256, 0, stream>>>(
        p20, c20, p40, c40, p80, c80, scores);

    nms_kernel<<<BATCH, 1024, 0, stream>>>(
        scores, b20, b40, b80, (float*)d_out);
}

// Round 12
// 148.951 us; speedup vs baseline: 1.3405x; 1.0127x over previous
//
#include <hip/hip_runtime.h>
#include <hip/hip_bf16.h>

#define NUM_CLASSES 80
#define BATCH 8
#define N20 1200
#define N40 4800
#define N80 19200
#define NANCH 25200
#define NEGV  -1000000000.0f
#define SCORE_THR 0.25f
#define CAP 2048            // candidate capacity (expected ~510/batch)
#define RMAX 192            // ranks materialized in the suppression matrix
#define PKCAP 512           // prefiltered participant capacity
#define NHBIN 1024          // histogram bins over the [64,128) octave
#define THR_LIST 64.0f      // candidate threshold (exact float)

typedef unsigned long long ull;

// ---------------------------------------------------------------------------
// Kernel 1: class argmax + score only (R10-proven). __launch_bounds__(256,3)
// grants ~170 VGPRs so all 20 dwordx4 loads stay in flight.
// ---------------------------------------------------------------------------
__global__ __launch_bounds__(256, 3) void score_kernel(
        const float* __restrict__ p20, const float* __restrict__ c20,
        const float* __restrict__ p40, const float* __restrict__ c40,
        const float* __restrict__ p80, const float* __restrict__ c80,
        float* __restrict__ scores) {
    const int t = threadIdx.x;
    const int b = blockIdx.y;
    const int an = blockIdx.x * 256 + t;
    const bool valid_an = (an < NANCH);
    const int n = valid_an ? an : (NANCH - 1);

    const float *cp, *pp;
    if (n < N20) {
        cp = c20 + ((size_t)b * N20 + n) * NUM_CLASSES;
        pp = p20 + (size_t)b * N20 + n;
    } else if (n < N20 + N40) {
        int a = n - N20;
        cp = c40 + ((size_t)b * N40 + a) * NUM_CLASSES;
        pp = p40 + (size_t)b * N40 + a;
    } else {
        int a = n - N20 - N40;
        cp = c80 + ((size_t)b * N80 + a) * NUM_CLASSES;
        pp = p80 + (size_t)b * N80 + a;
    }

    const float4* c4 = (const float4*)cp;
    float p = *pp;
    float4 v[20];
#pragma unroll
    for (int k = 0; k < 20; k++) v[k] = c4[k];
    __builtin_amdgcn_sched_barrier(0);   // keep all 20 loads above the argmax

    float best = -INFINITY;
    int bi = 0;
#pragma unroll
    for (int k = 0; k < 20; k++) {
        int basei = k * 4;
        if (v[k].x > best) { best = v[k].x; bi = basei; }
        if (v[k].y > best) { best = v[k].y; bi = basei + 1; }
        if (v[k].z > best) { best = v[k].z; bi = basei + 2; }
        if (v[k].w > best) { best = v[k].w; bi = basei + 3; }
    }

    float s = __fmul_rn(p, (float)bi);           // exact fp32, matches np
    float sval = (s > SCORE_THR) ? s : NEGV;
    if (valid_an) scores[(size_t)b * NANCH + an] = sval;   // coalesced
}

// exact IEEE fp32 (no FMA contraction) "IoU > 0.5" — matches numpy ref
__device__ __forceinline__ bool iou_gt(const float4 A, float areaA, const float4 Bx, float areaB) {
    float ih = fmaxf(__fsub_rn(fminf(A.z, Bx.z), fmaxf(A.x, Bx.x)), 0.0f);
    float iw = fmaxf(__fsub_rn(fminf(A.w, Bx.w), fmaxf(A.y, Bx.y)), 0.0f);
    float inter = __fmul_rn(ih, iw);
    float uni = __fsub_rn(__fadd_rn(areaA, areaB), inter);
    if (!(uni > 0.0f)) return false;
    return __fdiv_rn(inter, uni) > 0.5f;
}

// Same exact predicate with a division screen: if 2*inter < uni*(1-2^-23)
// then q_rn(inter/uni) <= 0.5 provably — skip the divide. Borderline pairs
// (rare) take the exact __fdiv_rn path — bit-identical decisions to numpy.
__device__ __forceinline__ bool iou_gt_fast(const float4 A, float areaA, const float4 Bx, float areaB) {
    float ih = fmaxf(__fsub_rn(fminf(A.z, Bx.z), fmaxf(A.x, Bx.x)), 0.0f);
    float iw = fmaxf(__fsub_rn(fminf(A.w, Bx.w), fmaxf(A.y, Bx.y)), 0.0f);
    float inter = __fmul_rn(ih, iw);
    float uni = __fsub_rn(__fadd_rn(areaA, areaB), inter);
    if (!(uni > 0.0f)) return false;
    if (__fmul_rn(2.0f, inter) < __fmul_rn(uni, 0.99999988f)) return false;
    return __fdiv_rn(inter, uni) > 0.5f;
}

__device__ __forceinline__ float4 load_box(int b, int n,
        const float* b20, const float* b40, const float* b80) {
    if (n < N20)       return ((const float4*)b20)[(size_t)b * N20 + n];
    if (n < N20 + N40) return ((const float4*)b40)[(size_t)b * N40 + (n - N20)];
    return ((const float4*)b80)[(size_t)b * N80 + (n - N20 - N40)];
}

__device__ __forceinline__ float box_area(const float4 B) {
    return __fmul_rn(__fsub_rn(B.z, B.x), __fsub_rn(B.w, B.y));
}

__device__ __forceinline__ int key_idx(ull k) {
    return (int)(0xFFFFFFFFu - (unsigned)(k & 0xFFFFFFFFull));
}

// ---------------------------------------------------------------------------
// Kernel 2: exact greedy NMS (R11 pipeline). Change vs R11: scan phase
// prefetches all 7 float4 loads (one latency exposure) and compacts with
// per-lane LDS atomics instead of 28 ballot-aggregation rounds. Key set
// identical; rank pass canonicalizes order — exactness unchanged.
// ---------------------------------------------------------------------------
__global__ __launch_bounds__(1024) void nms_kernel(
        float* __restrict__ scores,
        const float* __restrict__ b20, const float* __restrict__ b40,
        const float* __restrict__ b80, float* __restrict__ out) {
    __shared__ ull skeys[CAP];              // 16 KB
    __shared__ ull pk[PKCAP];               // 4 KB participants
    __shared__ unsigned hist[NHBIN];        // 4 KB
    __shared__ int prt[PKCAP][5];           // 10 KB (bank-padded rank partials)
    __shared__ ull srt_key[RMAX];           // 1.5 KB
    __shared__ float4 bboxC[4][RMAX + 1];   // 12.4 KB (4 bank-offset copies)
    __shared__ ull M[RMAX][3];              // 4.5 KB
    __shared__ ull red[1024];               // 8 KB (fallback argmax reduce)
    __shared__ int sh_V, sh_T;
    __shared__ unsigned sh_cnt, sh_pcnt;

    const int t = threadIdx.x;
    const int lane = t & 63;
    const int b = blockIdx.x;

    hist[t] = 0u;                       // NHBIN == blockDim == 1024
    if (t == 0) { sh_V = 0; sh_cnt = 0u; sh_pcnt = 0u; }
    __syncthreads();

    // ---- scan scores: prefetch all 7 loads, then per-lane atomic compact --
    const float4* sc4 = (const float4*)(scores + (size_t)b * NANCH);
    float4 s4[7];
#pragma unroll
    for (int it = 0; it < 7; it++) {            // 7*1024 >= 6300 (NANCH/4)
        const int i = t + it * 1024;
        s4[it] = (i < NANCH / 4) ? sc4[i] : make_float4(NEGV, NEGV, NEGV, NEGV);
    }
    __builtin_amdgcn_sched_barrier(0);          // all 7 loads in flight
#pragma unroll
    for (int it = 0; it < 7; it++) {
        const int i = t + it * 1024;
        const float sv[4] = {s4[it].x, s4[it].y, s4[it].z, s4[it].w};
#pragma unroll
        for (int c = 0; c < 4; c++) {
            if (sv[c] >= THR_LIST) {            // ~510 lanes total take this
                const unsigned sb = __float_as_uint(sv[c]);
                const unsigned an = (unsigned)(i * 4 + c);
                unsigned pos = atomicAdd(&sh_cnt, 1u);
                if (pos < (unsigned)CAP)
                    skeys[pos] = ((ull)sb << 32) | (ull)(0xFFFFFFFFu - an);
                atomicAdd(&hist[min((int)((sb - 0x42800000u) >> 13), NHBIN - 1)], 1u);
            }
        }
    }
    __syncthreads();

    const int cnt = (int)sh_cnt;
    const bool use_list = (cnt <= CAP);
    const int nR = use_list ? min(cnt, RMAX) : 0;
    const unsigned need = (unsigned)nR;

    if (use_list) {
        // wave 0: suffix-sum over 1024 bins; T = max bin with suffix >= need
        if (t < 64) {
            unsigned h[16], sfx[16];
            const int basei = t * 16;
#pragma unroll
            for (int k = 0; k < 16; k++) h[k] = hist[basei + k];
            unsigned run = 0;
#pragma unroll
            for (int k = 15; k >= 0; k--) { run += h[k]; sfx[k] = run; }
            unsigned s = run;
#pragma unroll
            for (int d = 1; d < 64; d <<= 1) {
                unsigned vv = __shfl_down(s, d);
                if (t + d < 64) s += vv;
            }
            const unsigned above = s - run;
            int bestb = -1;
#pragma unroll
            for (int k = 0; k < 16; k++)
                if (sfx[k] + above >= need) bestb = basei + k;   // ascending keeps max
#pragma unroll
            for (int d = 32; d > 0; d >>= 1) {
                int o = __shfl_down(bestb, d);
                if (t + d < 64) bestb = max(bestb, o);
            }
            if (t == 0) sh_T = max(bestb, 0);
        }
        __syncthreads();
        const int T = sh_T;

        // compact participants (2 wave-aggregated rounds over skeys)
#pragma unroll
        for (int h = 0; h < 2; h++) {
            const int c = t + h * 1024;
            bool part = false;
            ull k = 0ull;
            if (c < cnt) {
                k = skeys[c];
                int bin = min((int)(((unsigned)(k >> 32) - 0x42800000u) >> 13), NHBIN - 1);
                part = (bin >= T);
            }
            ull mask = __ballot(part);
            if (mask != 0ull) {
                int leader = (int)(__ffsll(mask) - 1);
                unsigned basep = 0;
                if (lane == leader) basep = atomicAdd(&sh_pcnt, (unsigned)__popcll(mask));
                basep = __shfl(basep, leader);
                if (part) {
                    unsigned pos = basep + (unsigned)__popcll(mask & ((1ull << lane) - 1));
                    if (pos < (unsigned)PKCAP) pk[pos] = k;
                }
            }
        }
        __syncthreads();
        const int m = (int)sh_pcnt;

        if (m <= PKCAP) {
            // prefetch my participant's box (in flight during rank)
            ull kmy = 0ull;
            float4 bmy = make_float4(0.f, 0.f, 0.f, 0.f);
            if (t < m) {
                kmy = pk[t];
                bmy = load_box(b, key_idx(kmy), b20, b40, b80);
            }
            // rank: thread (q,u) ranks pk[u], pk[u+256] over j-quarter q
            const int q = t >> 8, u = t & 255;
            const ull kA = (u < m) ? pk[u] : 0ull;
            const ull kB = (u + 256 < m) ? pk[u + 256] : 0ull;
            const int Q = (m + 3) >> 2;
            const int j0 = q * Q, j1 = min(m, j0 + Q);
            int rA = 0, rB = 0;
#pragma unroll 8
            for (int j = j0; j < j1; j++) {
                ull kj = pk[j];
                rA += (kj > kA) ? 1 : 0;
                rB += (kj > kB) ? 1 : 0;
            }
            prt[u][q] = rA;
            prt[u + 256][q] = rB;
            __syncthreads();
            if (t < m) {
                int r = prt[t][0] + prt[t][1] + prt[t][2] + prt[t][3];
                if (r < RMAX) {
                    srt_key[r] = kmy;
#pragma unroll
                    for (int c = 0; c < 4; c++) bboxC[c][r] = bmy;
                }
            }
            __syncthreads();
        } else {
            // guard: full rank of my 2 slots over all cnt keys
            ull kA = (t < cnt) ? skeys[t] : 0ull;
            ull kB = (t + 1024 < cnt) ? skeys[t + 1024] : 0ull;
            int rA = 0, rB = 0;
            for (int j = 0; j < cnt; j++) {
                ull kj = skeys[j];
                rA += (kj > kA) ? 1 : 0;
                rB += (kj > kB) ? 1 : 0;
            }
            if (t < cnt && rA < RMAX) srt_key[rA] = kA;
            if (t + 1024 < cnt && rB < RMAX) srt_key[rB] = kB;
            __syncthreads();
            if (t < nR) {
                float4 B = load_box(b, key_idx(srt_key[t]), b20, b40, b80);
#pragma unroll
                for (int c = 0; c < 4; c++) bboxC[c][t] = B;
            }
            __syncthreads();
        }

        // suppression matrix: M[row][cw] bit j = (rank cw*64+j suppresses row)
        // bboxC bank layout: dword-bank = (4*cw + 4*j) % 32 — disjoint per cw.
        {
            const int row = t >> 2, cw = t & 3;
            if (row < RMAX && cw < 3) {
                ull w = 0ull;
                if (row < nR && cw * 64 < row) {
                    const float4 B = bboxC[cw][row];
                    const float aB = box_area(B);
                    const int jmax = min(64, row - cw * 64);
                    const float4* src = &bboxC[cw][cw * 64];
                    for (int j = 0; j < jmax; j++) {
                        const float4 C = src[j];
                        w |= ((ull)iou_gt_fast(C, box_area(C), B, aB)) << j;
                    }
                }
                M[row][cw] = w;
            }
        }
        __syncthreads();

        // greedy resolution: wave 0, accepted-set in registers (pure VALU)
        int v = 0;
        if (t < 64) {
            ull A0 = 0, A1 = 0, A2 = 0;
            for (int rg = 0; rg < 3 && v < 100; rg++) {
                const int rr = rg * 64 + t;
                const bool valid = (rr < nR);
                ull w0 = 0, w1 = 0, w2 = 0;
                if (valid) { w0 = M[rr][0]; w1 = M[rr][1]; w2 = M[rr][2]; }
                const ull mw = (rg == 0) ? w0 : (rg == 1) ? w1 : w2;
                const bool supE = !valid ||
                    (((w0 & A0) | (w1 & A1) | (w2 & A2)) != 0ull);
                ull alive = __ballot(!supE);
                while (alive != 0ull && v < 100) {
                    int c = (int)(__ffsll(alive) - 1);
                    ull supc = __ballot((bool)((mw >> c) & 1ull));
                    alive &= ~(supc | (1ull << c));
                    if (rg == 0) A0 |= 1ull << c;
                    else if (rg == 1) A1 |= 1ull << c;
                    else A2 |= 1ull << c;
                    if (t == c) {
                        const float4 B = bboxC[0][rr];
                        float* rowp = out + ((size_t)b * 100 + v) * 6;
                        rowp[0] = fminf(fmaxf(B.x, 0.f), 1.f);
                        rowp[1] = fminf(fmaxf(B.y, 0.f), 1.f);
                        rowp[2] = fminf(fmaxf(B.z, 0.f), 1.f);
                        rowp[3] = fminf(fmaxf(B.w, 0.f), 1.f);
                        rowp[4] = __uint_as_float((unsigned)(srt_key[rr] >> 32));
                        rowp[5] = 0.f;
                    }
                    v++;
                }
            }
            if (t == 0) sh_V = v;
        }
        __syncthreads();
    }

    // ------- exact fallback: reference-style greedy (never taken here) -----
    const bool need_fb = (!use_list) || (sh_V < 100 && cnt > nR);
    if (need_fb) {
        float* scb = scores + (size_t)b * NANCH;
        int v2 = 0;
        for (int k = 0; k < 100; k++) {
            ull bestk = 0ull;
            for (int i = t; i < NANCH; i += 1024) {
                float sv = scb[i];
                unsigned u = __float_as_uint(sv);
                u ^= (u & 0x80000000u) ? 0xFFFFFFFFu : 0x80000000u;
                ull key = ((ull)u << 32) | (ull)(0xFFFFFFFFu - (unsigned)i);
                if (key > bestk) bestk = key;
            }
            red[t] = bestk;
            __syncthreads();
            for (int ss = 512; ss > 0; ss >>= 1) {
                if (t < ss && red[t + ss] > red[t]) red[t] = red[t + ss];
                __syncthreads();
            }
            ull bk = red[0];
            __syncthreads();
            unsigned u = (unsigned)(bk >> 32);
            u ^= (u & 0x80000000u) ? 0x80000000u : 0xFFFFFFFFu;
            float s = __uint_as_float(u);
            int idx = (int)(0xFFFFFFFFu - (unsigned)(bk & 0xFFFFFFFFull));
            if (!(s > NEGV * 0.5f)) break;                  // wave-uniform
            float4 B = load_box(b, idx, b20, b40, b80);
            float aB = box_area(B);
            for (int i = t; i < NANCH; i += 1024) {
                float sv = scb[i];
                if (sv > NEGV * 0.5f) {
                    float4 C = load_box(b, i, b20, b40, b80);
                    if (iou_gt(B, aB, C, box_area(C))) scb[i] = NEGV;
                }
            }
            if (t == 0) {
                scb[idx] = NEGV;
                float* rowp = out + ((size_t)b * 100 + k) * 6;
                rowp[0] = fminf(fmaxf(B.x, 0.f), 1.f);
                rowp[1] = fminf(fmaxf(B.y, 0.f), 1.f);
                rowp[2] = fminf(fmaxf(B.z, 0.f), 1.f);
                rowp[3] = fminf(fmaxf(B.w, 0.f), 1.f);
                rowp[4] = s;
                rowp[5] = 0.f;
            }
            v2++;
            __syncthreads();
        }
        __syncthreads();
        if (t == 0) sh_V = v2;
        __syncthreads();
    }

    const int V = sh_V;
    for (int i = V * 6 + t; i < 600; i += 1024) out[(size_t)b * 600 + i] = 0.f;
    if (t == 0) out[4800 + b] = (float)V;
}

extern "C" void kernel_launch(void* const* d_in, const int* in_sizes, int n_in,
                              void* d_out, int out_size, void* d_ws, size_t ws_size,
                              hipStream_t stream) {
    const float* b20 = (const float*)d_in[0];
    const float* p20 = (const float*)d_in[1];
    const float* c20 = (const float*)d_in[2];
    const float* b40 = (const float*)d_in[3];
    const float* p40 = (const float*)d_in[4];
    const float* c40 = (const float*)d_in[5];
    const float* b80 = (const float*)d_in[6];
    const float* p80 = (const float*)d_in[7];
    const float* c80 = (const float*)d_in[8];

    float* scores = (float*)d_ws;                 // 806400 B

    dim3 sgrid((NANCH + 255) / 256, BATCH);
    score_kernel<<<sgrid, 256, 0, stream>>>(
        p20, c20, p40, c40, p80, c80, scores);

    nms_kernel<<<BATCH, 1024, 0, stream>>>(
        scores, b20, b40, b80, (float*)d_out);
}